// Round 3
// baseline (1519.400 us; speedup 1.0000x reference)
//
#include <hip/hip_runtime.h>

typedef float f32x4 __attribute__((ext_vector_type(4)));
typedef short bf16x8 __attribute__((ext_vector_type(8)));

#define T_LEN 96
#define DM    256
#define NSAMP 64      // ODE rows per block
#define MT 2          // d-tiles per wave (wave owns 32 d)
#define NT 4          // sample-tiles per wave (64 samples)

__device__ __forceinline__ uint bf16h(float x){            // f32 -> bf16 bits, RNE
    uint u = __float_as_uint(x);
    return (u + 0x7fffu + ((u>>16)&1u)) >> 16;
}
__device__ __forceinline__ float bf16f(uint h){ return __uint_as_float(h<<16); }
__device__ __forceinline__ float softplus_f(float x){
    return fmaxf(x,0.f) + log1pf(__expf(-fabsf(x)));
}

// Split W into bf16 hi/lo and pack into MFMA A-fragment order:
// frag (dt,ks): lane l holds W[dt*16 + (l&15)][ks*32 + (l>>4)*8 + i], i=0..7
// => packed[((dt*8+ks)*64 + l)*8 + i]; wave64 load = contiguous 1KB.
__global__ void pack_w_kernel(const float* __restrict__ W1, const float* __restrict__ W2,
                              ushort* __restrict__ ws){
    int idx = blockIdx.x*256 + threadIdx.x;          // 0..65535
    const float* W = blockIdx.y ? W2 : W1;
    ushort* hi = ws + (size_t)blockIdx.y*131072;     // [W1hi|W1lo|W2hi|W2lo], 65536 each
    ushort* lo = hi + 65536;
    float w = W[idx];
    uint h = bf16h(w);
    float l = w - bf16f(h);
    uint l16 = bf16h(l);
    int d = idx >> 8, k = idx & 255;
    int off = ((((d>>4)<<3) + (k>>5))<<9) + (((d&15) | (((k>>3)&3)<<4))<<3) + (k&7);
    hi[off] = (ushort)h;
    lo[off] = (ushort)l16;
}

__global__ __launch_bounds__(512, 2)
void ode_mfma_kernel(const float* __restrict__ x, const float* __restrict__ t,
                     const float* __restrict__ b1, const float* __restrict__ u1,
                     const float* __restrict__ b2, const float* __restrict__ u2,
                     const ushort* __restrict__ wpk, float* __restrict__ out)
{
    // Y stage: [row 0..63][hi 256 | lo 256] bf16; 16B granules XOR-swizzled by (row&7)
    // (bank = addr bits 2..6 -> granule bits 0..2; row stride 1024B contributes 0)
    __shared__ __align__(16) ushort ylds[NSAMP*512];

    const int tid  = threadIdx.x;
    const int wv   = tid >> 6;      // wave 0..7 -> d in [32w, 32w+32)
    const int lane = tid & 63;
    const int l15  = lane & 15;
    const int l4   = lane >> 4;
    const int base = blockIdx.x * NSAMP;

    int   bj[NT];
    float t0v[NT], rat[NT];
#pragma unroll
    for(int nt=0; nt<NT; nt++){
        int n = base + nt*16 + l15;
        int b = n / (T_LEN*T_LEN);
        int r = n - b*(T_LEN*T_LEN);
        int q = r / T_LEN;
        int j = r - q*T_LEN;
        bj[nt] = b*T_LEN + j;
        float ta = t[b*T_LEN + j], tb = t[b*T_LEN + q];
        t0v[nt] = ta; rat[nt] = tb - ta;
    }

    float y[MT][NT][4], k1[MT][NT][4], k2[MT][NT][4];
    f32x4 acc[MT][NT];

#pragma unroll
    for(int mt=0; mt<MT; mt++){
        const int db = 32*wv + mt*16 + l4*4;
#pragma unroll
        for(int nt=0; nt<NT; nt++){
            f32x4 v = *(const f32x4*)(x + (size_t)bj[nt]*DM + db);
#pragma unroll
            for(int r2=0;r2<4;r2++) y[mt][nt][r2] = v[r2];
        }
    }

    // write 4 consecutive-d values (one D-fragment reg group) as hi/lo bf16 into ylds
    auto put = [&](int mt, int nt, float v0, float v1, float v2, float v3){
        uint h0=bf16h(v0), h1=bf16h(v1), h2=bf16h(v2), h3=bf16h(v3);
        uint hp0 = h0 | (h1<<16), hp1 = h2 | (h3<<16);
        uint lp0 = bf16h(v0 - bf16f(h0)) | (bf16h(v1 - bf16f(h1))<<16);
        uint lp1 = bf16h(v2 - bf16f(h2)) | (bf16h(v3 - bf16f(h3))<<16);
        int row = nt*16 + l15;
        int col = 4*wv + 2*mt + (l4>>1);        // logical 16B granule (8 ushort = 8 k)
        int g   = col ^ (row & 7);              // swizzle low 3 granule bits
        int idx = row*512 + g*8 + (l4&1)*4;
        *(uint2*)&ylds[idx]       = make_uint2(hp0, hp1);   // hi half
        *(uint2*)&ylds[idx + 256] = make_uint2(lp0, lp1);   // lo half
    };

    // acc[mt][nt] = (W-slice) x Y^T over K=256, 3-product bf16 split
    auto matmul = [&](const ushort* Whi){
        const ushort* Wlo = Whi + 65536;
#pragma unroll
        for(int mt=0; mt<MT; mt++)
#pragma unroll
            for(int nt=0; nt<NT; nt++)
                acc[mt][nt] = (f32x4){0.f,0.f,0.f,0.f};
#pragma unroll 2
        for(int ks=0; ks<8; ks++){
            bf16x8 ah[MT], al[MT];
#pragma unroll
            for(int mt=0; mt<MT; mt++){
                const int off = ((((2*wv+mt)<<3)+ks)<<9) + (lane<<3);
                ah[mt] = *(const bf16x8*)(Whi + off);
                al[mt] = *(const bf16x8*)(Wlo + off);
            }
            bf16x8 bh[NT], bl[NT];
#pragma unroll
            for(int nt=0; nt<NT; nt++){
                const int row = nt*16 + l15;
                const int gx  = (ks*4 + l4) ^ (row & 7);    // logical granule ks*4+l4
                const ushort* bp = &ylds[row*512 + gx*8];
                bh[nt] = *(const bf16x8*)bp;
                bl[nt] = *(const bf16x8*)(bp + 256);
            }
#pragma unroll
            for(int mt=0; mt<MT; mt++)
#pragma unroll
                for(int nt=0; nt<NT; nt++){
                    acc[mt][nt] = __builtin_amdgcn_mfma_f32_16x16x32_bf16(ah[mt], bh[nt], acc[mt][nt], 0,0,0);
                    acc[mt][nt] = __builtin_amdgcn_mfma_f32_16x16x32_bf16(ah[mt], bl[nt], acc[mt][nt], 0,0,0);
                    acc[mt][nt] = __builtin_amdgcn_mfma_f32_16x16x32_bf16(al[mt], bh[nt], acc[mt][nt], 0,0,0);
                }
        }
    };

    // input already staged by caller; leaves layer-2 raw acc for caller to finish
    auto eval = [&](const float* ttv){
        __syncthreads();                 // stage writes visible
        matmul(wpk);                     // layer 1
        __syncthreads();                 // all reads of input stage done
#pragma unroll
        for(int mt=0; mt<MT; mt++){
            const int db = 32*wv + mt*16 + l4*4;
            f32x4 bv = *(const f32x4*)(b1 + db);
            f32x4 uv = *(const f32x4*)(u1 + db);
#pragma unroll
            for(int nt=0; nt<NT; nt++){
                float v[4];
#pragma unroll
                for(int r2=0;r2<4;r2++)
                    v[r2] = softplus_f(acc[mt][nt][r2] + bv[r2] + ttv[nt]*uv[r2]);
                put(mt, nt, v[0], v[1], v[2], v[3]);
            }
        }
        __syncthreads();
        matmul(wpk + 131072);            // layer 2
    };

    float s0 = 0.f;
#pragma unroll 1
    for(int step=0; step<3; step++){
        const float s1 = (step==0) ? 0.1127016653792583f : ((step==1) ? 0.5f : 0.8872983346207417f);
        const float gw = ((step==1) ? 0.88888f : 0.55555f) * 0.5f;
        const float dt = s1 - s0;
        const float c3 = dt * (1.f/3.f);
        const float dt8 = dt * 0.125f;
        float tt[NT];

        // ---- eval 1: f(s0, y) -> k1
        __syncthreads();                 // prior step's transpose reads done
#pragma unroll
        for(int mt=0; mt<MT; mt++)
#pragma unroll
            for(int nt=0; nt<NT; nt++)
                put(mt, nt, y[mt][nt][0], y[mt][nt][1], y[mt][nt][2], y[mt][nt][3]);
#pragma unroll
        for(int nt=0; nt<NT; nt++) tt[nt] = t0v[nt] + s0*rat[nt];
        eval(tt);

        // ---- k1 extract; stage y + (dt/3)k1
        __syncthreads();
#pragma unroll
        for(int mt=0; mt<MT; mt++){
            const int db = 32*wv + mt*16 + l4*4;
            f32x4 bv = *(const f32x4*)(b2 + db);
            f32x4 uv = *(const f32x4*)(u2 + db);
#pragma unroll
            for(int nt=0; nt<NT; nt++){
                float v[4];
#pragma unroll
                for(int r2=0;r2<4;r2++){
                    float kk = (acc[mt][nt][r2] + bv[r2] + tt[nt]*uv[r2]) * rat[nt];
                    k1[mt][nt][r2] = kk;
                    v[r2] = fmaf(c3, kk, y[mt][nt][r2]);
                }
                put(mt, nt, v[0], v[1], v[2], v[3]);
            }
        }
#pragma unroll
        for(int nt=0; nt<NT; nt++) tt[nt] = t0v[nt] + (s0+c3)*rat[nt];
        eval(tt);

        // ---- k2 extract; stage y + dt*k2 - (dt/3)k1
        __syncthreads();
#pragma unroll
        for(int mt=0; mt<MT; mt++){
            const int db = 32*wv + mt*16 + l4*4;
            f32x4 bv = *(const f32x4*)(b2 + db);
            f32x4 uv = *(const f32x4*)(u2 + db);
#pragma unroll
            for(int nt=0; nt<NT; nt++){
                float v[4];
#pragma unroll
                for(int r2=0;r2<4;r2++){
                    float kk = (acc[mt][nt][r2] + bv[r2] + tt[nt]*uv[r2]) * rat[nt];
                    k2[mt][nt][r2] = kk;
                    v[r2] = y[mt][nt][r2] + dt*kk - c3*k1[mt][nt][r2];
                }
                put(mt, nt, v[0], v[1], v[2], v[3]);
            }
        }
#pragma unroll
        for(int nt=0; nt<NT; nt++) tt[nt] = t0v[nt] + (s0+2.f*c3)*rat[nt];
        eval(tt);

        // ---- k3 extract (folded): stage y + dt*(k1-k2+k3); y += dt8*(k1+3(k2+k3))
        __syncthreads();
#pragma unroll
        for(int mt=0; mt<MT; mt++){
            const int db = 32*wv + mt*16 + l4*4;
            f32x4 bv = *(const f32x4*)(b2 + db);
            f32x4 uv = *(const f32x4*)(u2 + db);
#pragma unroll
            for(int nt=0; nt<NT; nt++){
                float v[4];
#pragma unroll
                for(int r2=0;r2<4;r2++){
                    float k3v = (acc[mt][nt][r2] + bv[r2] + tt[nt]*uv[r2]) * rat[nt];
                    float yo = y[mt][nt][r2];
                    v[r2] = yo + dt*(k1[mt][nt][r2] - k2[mt][nt][r2] + k3v);
                    y[mt][nt][r2] = yo + dt8*(k1[mt][nt][r2] + 3.f*(k2[mt][nt][r2] + k3v));
                }
                put(mt, nt, v[0], v[1], v[2], v[3]);
            }
        }
#pragma unroll
        for(int nt=0; nt<NT; nt++) tt[nt] = t0v[nt] + s1*rat[nt];
        eval(tt);

        // ---- k4 fold, then transpose through LDS for coalesced output
        __syncthreads();                 // matmul2 reads of ylds done; safe to overwrite
        {
            float* yf = (float*)ylds;    // view: [64 rows][256 f32], 16B-granule swizzled
#pragma unroll
            for(int mt=0; mt<MT; mt++){
                const int db = 32*wv + mt*16 + l4*4;
                f32x4 bv = *(const f32x4*)(b2 + db);
                f32x4 uv = *(const f32x4*)(u2 + db);
#pragma unroll
                for(int nt=0; nt<NT; nt++){
                    const int row = nt*16 + l15;
                    f32x4 ov;
#pragma unroll
                    for(int r2=0;r2<4;r2++){
                        float k4v = (acc[mt][nt][r2] + bv[r2] + tt[nt]*uv[r2]) * rat[nt];
                        float yn = fmaf(dt8, k4v, y[mt][nt][r2]);
                        y[mt][nt][r2] = yn;
                        ov[r2] = yn * gw;
                    }
                    const int c = 8*wv + 4*mt + l4;          // logical 16B granule = d>>2
                    const int p = c ^ (row & 7);
                    *(f32x4*)&yf[row*256 + p*4] = ov;
                }
            }
            __syncthreads();
            // each wave stores 8 rows, 1KB contiguous per row
#pragma unroll
            for(int i=0;i<8;i++){
                const int r = 8*wv + i;
                f32x4 v = *(const f32x4*)&yf[r*256 + (lane ^ i)*4];
                *(f32x4*)(out + ((size_t)(base + r)*3 + step)*DM + lane*4) = v;
            }
        }
        s0 = s1;
    }
}

extern "C" void kernel_launch(void* const* d_in, const int* in_sizes, int n_in,
                              void* d_out, int out_size, void* d_ws, size_t ws_size,
                              hipStream_t stream)
{
    const float* x  = (const float*)d_in[0];
    const float* t  = (const float*)d_in[1];
    const float* W1 = (const float*)d_in[2];
    const float* b1 = (const float*)d_in[3];
    const float* u1 = (const float*)d_in[4];
    const float* W2 = (const float*)d_in[5];
    const float* b2 = (const float*)d_in[6];
    const float* u2 = (const float*)d_in[7];
    ushort* wpk = (ushort*)d_ws;     // 512 KB: W1hi|W1lo|W2hi|W2lo packed fragments

    pack_w_kernel<<<dim3(256,2), 256, 0, stream>>>(W1, W2, wpk);
    ode_mfma_kernel<<<dim3((4*T_LEN*T_LEN)/NSAMP), 512, 0, stream>>>(
        x, t, b1, u1, b2, u2, wpk, (float*)d_out);
}

// Round 4
// 1513.172 us; speedup vs baseline: 1.0041x; 1.0041x over previous
//
#include <hip/hip_runtime.h>

typedef float f32x4 __attribute__((ext_vector_type(4)));
typedef short bf16x8 __attribute__((ext_vector_type(8)));

#define T_LEN 96
#define DM    256
#define NSAMP 64      // ODE rows per block
#define MT 2          // d-tiles per wave (wave owns 32 d)
#define NT 4          // sample-tiles per wave (64 samples)

__device__ __forceinline__ uint bf16h(float x){            // f32 -> bf16 bits, RNE
    uint u = __float_as_uint(x);
    return (u + 0x7fffu + ((u>>16)&1u)) >> 16;
}
__device__ __forceinline__ float bf16f(uint h){ return __uint_as_float(h<<16); }
__device__ __forceinline__ float softplus_f(float x){
    return fmaxf(x,0.f) + log1pf(__expf(-fabsf(x)));
}

// Split W into bf16 hi/lo and pack into MFMA A-fragment order:
// frag (dt,ks): lane l holds W[dt*16 + (l&15)][ks*32 + (l>>4)*8 + i], i=0..7
// => packed[((dt*8+ks)*64 + l)*8 + i]; wave64 load = contiguous 1KB.
__global__ void pack_w_kernel(const float* __restrict__ W1, const float* __restrict__ W2,
                              ushort* __restrict__ ws){
    int idx = blockIdx.x*256 + threadIdx.x;          // 0..65535
    const float* W = blockIdx.y ? W2 : W1;
    ushort* hi = ws + (size_t)blockIdx.y*131072;     // [W1hi|W1lo|W2hi|W2lo], 65536 each
    ushort* lo = hi + 65536;
    float w = W[idx];
    uint h = bf16h(w);
    float l = w - bf16f(h);
    uint l16 = bf16h(l);
    int d = idx >> 8, k = idx & 255;
    int off = ((((d>>4)<<3) + (k>>5))<<9) + (((d&15) | (((k>>3)&3)<<4))<<3) + (k&7);
    hi[off] = (ushort)h;
    lo[off] = (ushort)l16;
}

__global__ __launch_bounds__(512, 2)
void ode_mfma_kernel(const float* __restrict__ x, const float* __restrict__ t,
                     const float* __restrict__ b1, const float* __restrict__ u1,
                     const float* __restrict__ b2, const float* __restrict__ u2,
                     const ushort* __restrict__ wpk, float* __restrict__ out)
{
    // Y stage: [row 0..63][hi 256 | lo 256] bf16; 16B granules XOR-swizzled by (row&7)
    // (bank = addr bits 2..6 -> granule bits 0..2; row stride 1024B contributes 0)
    __shared__ __align__(16) ushort ylds[NSAMP*512];

    const int tid  = threadIdx.x;
    const int wv   = tid >> 6;      // wave 0..7 -> d in [32w, 32w+32)
    const int lane = tid & 63;
    const int l15  = lane & 15;
    const int l4   = lane >> 4;
    const int base = blockIdx.x * NSAMP;

    int   bj[NT];
    float t0v[NT], rat[NT];
#pragma unroll
    for(int nt=0; nt<NT; nt++){
        int n = base + nt*16 + l15;
        int b = n / (T_LEN*T_LEN);
        int r = n - b*(T_LEN*T_LEN);
        int q = r / T_LEN;
        int j = r - q*T_LEN;
        bj[nt] = b*T_LEN + j;
        float ta = t[b*T_LEN + j], tb = t[b*T_LEN + q];
        t0v[nt] = ta; rat[nt] = tb - ta;
    }

    float y[MT][NT][4], k1[MT][NT][4], k2[MT][NT][4];
    f32x4 acc[MT][NT];

#pragma unroll
    for(int mt=0; mt<MT; mt++){
        const int db = 32*wv + mt*16 + l4*4;
#pragma unroll
        for(int nt=0; nt<NT; nt++){
            f32x4 v = *(const f32x4*)(x + (size_t)bj[nt]*DM + db);
#pragma unroll
            for(int r2=0;r2<4;r2++) y[mt][nt][r2] = v[r2];
        }
    }

    // write 4 consecutive-d values (one D-fragment reg group) as hi/lo bf16 into ylds
    auto put = [&](int mt, int nt, float v0, float v1, float v2, float v3){
        uint h0=bf16h(v0), h1=bf16h(v1), h2=bf16h(v2), h3=bf16h(v3);
        uint hp0 = h0 | (h1<<16), hp1 = h2 | (h3<<16);
        uint lp0 = bf16h(v0 - bf16f(h0)) | (bf16h(v1 - bf16f(h1))<<16);
        uint lp1 = bf16h(v2 - bf16f(h2)) | (bf16h(v3 - bf16f(h3))<<16);
        int row = nt*16 + l15;
        int col = 4*wv + 2*mt + (l4>>1);        // logical 16B granule (8 ushort = 8 k)
        int g   = col ^ (row & 7);              // swizzle low 3 granule bits
        int idx = row*512 + g*8 + (l4&1)*4;
        *(uint2*)&ylds[idx]       = make_uint2(hp0, hp1);   // hi half
        *(uint2*)&ylds[idx + 256] = make_uint2(lp0, lp1);   // lo half
    };

    // acc[mt][nt] = (W-slice) x Y^T over K=256, 3-product bf16 split
    auto matmul = [&](const ushort* Whi){
        const ushort* Wlo = Whi + 65536;
#pragma unroll
        for(int mt=0; mt<MT; mt++)
#pragma unroll
            for(int nt=0; nt<NT; nt++)
                acc[mt][nt] = (f32x4){0.f,0.f,0.f,0.f};
#pragma unroll 2
        for(int ks=0; ks<8; ks++){
            bf16x8 ah[MT], al[MT];
#pragma unroll
            for(int mt=0; mt<MT; mt++){
                const int off = ((((2*wv+mt)<<3)+ks)<<9) + (lane<<3);
                ah[mt] = *(const bf16x8*)(Whi + off);
                al[mt] = *(const bf16x8*)(Wlo + off);
            }
            bf16x8 bh[NT], bl[NT];
#pragma unroll
            for(int nt=0; nt<NT; nt++){
                const int row = nt*16 + l15;
                const int gx  = (ks*4 + l4) ^ (row & 7);    // logical granule ks*4+l4
                const ushort* bp = &ylds[row*512 + gx*8];
                bh[nt] = *(const bf16x8*)bp;
                bl[nt] = *(const bf16x8*)(bp + 256);
            }
#pragma unroll
            for(int mt=0; mt<MT; mt++)
#pragma unroll
                for(int nt=0; nt<NT; nt++){
                    acc[mt][nt] = __builtin_amdgcn_mfma_f32_16x16x32_bf16(ah[mt], bh[nt], acc[mt][nt], 0,0,0);
                    acc[mt][nt] = __builtin_amdgcn_mfma_f32_16x16x32_bf16(ah[mt], bl[nt], acc[mt][nt], 0,0,0);
                    acc[mt][nt] = __builtin_amdgcn_mfma_f32_16x16x32_bf16(al[mt], bh[nt], acc[mt][nt], 0,0,0);
                }
        }
    };

    // input already staged by caller; leaves layer-2 raw acc for caller to finish
    auto eval = [&](const float* ttv){
        __syncthreads();                 // stage writes visible
        matmul(wpk);                     // layer 1
        __syncthreads();                 // all reads of input stage done
#pragma unroll
        for(int mt=0; mt<MT; mt++){
            const int db = 32*wv + mt*16 + l4*4;
            f32x4 bv = *(const f32x4*)(b1 + db);
            f32x4 uv = *(const f32x4*)(u1 + db);
#pragma unroll
            for(int nt=0; nt<NT; nt++){
                float v[4];
#pragma unroll
                for(int r2=0;r2<4;r2++)
                    v[r2] = softplus_f(acc[mt][nt][r2] + bv[r2] + ttv[nt]*uv[r2]);
                put(mt, nt, v[0], v[1], v[2], v[3]);
            }
        }
        __syncthreads();
        matmul(wpk + 131072);            // layer 2
    };

    float s0 = 0.f;
#pragma unroll 1
    for(int step=0; step<3; step++){
        const float s1 = (step==0) ? 0.1127016653792583f : ((step==1) ? 0.5f : 0.8872983346207417f);
        const float gw = ((step==1) ? 0.88888f : 0.55555f) * 0.5f;
        const float dt = s1 - s0;
        const float c3 = dt * (1.f/3.f);
        const float dt8 = dt * 0.125f;
        float tt[NT];

        // ---- eval 1: f(s0, y) -> k1
        __syncthreads();                 // prior step's transpose reads done
#pragma unroll
        for(int mt=0; mt<MT; mt++)
#pragma unroll
            for(int nt=0; nt<NT; nt++)
                put(mt, nt, y[mt][nt][0], y[mt][nt][1], y[mt][nt][2], y[mt][nt][3]);
#pragma unroll
        for(int nt=0; nt<NT; nt++) tt[nt] = t0v[nt] + s0*rat[nt];
        eval(tt);

        // ---- k1 extract; stage y + (dt/3)k1
        __syncthreads();
#pragma unroll
        for(int mt=0; mt<MT; mt++){
            const int db = 32*wv + mt*16 + l4*4;
            f32x4 bv = *(const f32x4*)(b2 + db);
            f32x4 uv = *(const f32x4*)(u2 + db);
#pragma unroll
            for(int nt=0; nt<NT; nt++){
                float v[4];
#pragma unroll
                for(int r2=0;r2<4;r2++){
                    float kk = (acc[mt][nt][r2] + bv[r2] + tt[nt]*uv[r2]) * rat[nt];
                    k1[mt][nt][r2] = kk;
                    v[r2] = fmaf(c3, kk, y[mt][nt][r2]);
                }
                put(mt, nt, v[0], v[1], v[2], v[3]);
            }
        }
#pragma unroll
        for(int nt=0; nt<NT; nt++) tt[nt] = t0v[nt] + (s0+c3)*rat[nt];
        eval(tt);

        // ---- k2 extract; stage y + dt*k2 - (dt/3)k1
        __syncthreads();
#pragma unroll
        for(int mt=0; mt<MT; mt++){
            const int db = 32*wv + mt*16 + l4*4;
            f32x4 bv = *(const f32x4*)(b2 + db);
            f32x4 uv = *(const f32x4*)(u2 + db);
#pragma unroll
            for(int nt=0; nt<NT; nt++){
                float v[4];
#pragma unroll
                for(int r2=0;r2<4;r2++){
                    float kk = (acc[mt][nt][r2] + bv[r2] + tt[nt]*uv[r2]) * rat[nt];
                    k2[mt][nt][r2] = kk;
                    v[r2] = y[mt][nt][r2] + dt*kk - c3*k1[mt][nt][r2];
                }
                put(mt, nt, v[0], v[1], v[2], v[3]);
            }
        }
#pragma unroll
        for(int nt=0; nt<NT; nt++) tt[nt] = t0v[nt] + (s0+2.f*c3)*rat[nt];
        eval(tt);

        // ---- k3 extract (folded): stage y + dt*(k1-k2+k3); y += dt8*(k1+3(k2+k3))
        __syncthreads();
#pragma unroll
        for(int mt=0; mt<MT; mt++){
            const int db = 32*wv + mt*16 + l4*4;
            f32x4 bv = *(const f32x4*)(b2 + db);
            f32x4 uv = *(const f32x4*)(u2 + db);
#pragma unroll
            for(int nt=0; nt<NT; nt++){
                float v[4];
#pragma unroll
                for(int r2=0;r2<4;r2++){
                    float k3v = (acc[mt][nt][r2] + bv[r2] + tt[nt]*uv[r2]) * rat[nt];
                    float yo = y[mt][nt][r2];
                    v[r2] = yo + dt*(k1[mt][nt][r2] - k2[mt][nt][r2] + k3v);
                    y[mt][nt][r2] = yo + dt8*(k1[mt][nt][r2] + 3.f*(k2[mt][nt][r2] + k3v));
                }
                put(mt, nt, v[0], v[1], v[2], v[3]);
            }
        }
#pragma unroll
        for(int nt=0; nt<NT; nt++) tt[nt] = t0v[nt] + s1*rat[nt];
        eval(tt);

        // ---- k4 fold, then transpose through LDS for coalesced output
        __syncthreads();                 // matmul2 reads of ylds done; safe to overwrite
        {
            float* yf = (float*)ylds;    // view: [64 rows][256 f32], 16B-granule swizzled
#pragma unroll
            for(int mt=0; mt<MT; mt++){
                const int db = 32*wv + mt*16 + l4*4;
                f32x4 bv = *(const f32x4*)(b2 + db);
                f32x4 uv = *(const f32x4*)(u2 + db);
#pragma unroll
                for(int nt=0; nt<NT; nt++){
                    const int row = nt*16 + l15;
                    f32x4 ov;
#pragma unroll
                    for(int r2=0;r2<4;r2++){
                        float k4v = (acc[mt][nt][r2] + bv[r2] + tt[nt]*uv[r2]) * rat[nt];
                        float yn = fmaf(dt8, k4v, y[mt][nt][r2]);
                        y[mt][nt][r2] = yn;
                        ov[r2] = yn * gw;
                    }
                    const int c = 8*wv + 4*mt + l4;          // logical 16B granule = d>>2
                    const int p = c ^ (row & 7);
                    *(f32x4*)&yf[row*256 + p*4] = ov;
                }
            }
            __syncthreads();
            // each wave stores 8 rows, 1KB contiguous per row — NON-TEMPORAL:
            // don't let the 113MB output stream evict the 512KB packed-W from L2
#pragma unroll
            for(int i=0;i<8;i++){
                const int r = 8*wv + i;
                f32x4 v = *(const f32x4*)&yf[r*256 + (lane ^ i)*4];
                __builtin_nontemporal_store(v,
                    (f32x4*)(out + ((size_t)(base + r)*3 + step)*DM + lane*4));
            }
        }
        s0 = s1;
    }
}

extern "C" void kernel_launch(void* const* d_in, const int* in_sizes, int n_in,
                              void* d_out, int out_size, void* d_ws, size_t ws_size,
                              hipStream_t stream)
{
    const float* x  = (const float*)d_in[0];
    const float* t  = (const float*)d_in[1];
    const float* W1 = (const float*)d_in[2];
    const float* b1 = (const float*)d_in[3];
    const float* u1 = (const float*)d_in[4];
    const float* W2 = (const float*)d_in[5];
    const float* b2 = (const float*)d_in[6];
    const float* u2 = (const float*)d_in[7];
    ushort* wpk = (ushort*)d_ws;     // 512 KB: W1hi|W1lo|W2hi|W2lo packed fragments

    pack_w_kernel<<<dim3(256,2), 256, 0, stream>>>(W1, W2, wpk);
    ode_mfma_kernel<<<dim3((4*T_LEN*T_LEN)/NSAMP), 512, 0, stream>>>(
        x, t, b1, u1, b2, u2, wpk, (float*)d_out);
}

// Round 5
// 1469.196 us; speedup vs baseline: 1.0342x; 1.0299x over previous
//
#include <hip/hip_runtime.h>

typedef float f32x4 __attribute__((ext_vector_type(4)));
typedef short bf16x8 __attribute__((ext_vector_type(8)));

#define T_LEN 96
#define DM    256
#define NSAMP 64      // ODE rows per block
#define MT 2          // d-tiles per wave (wave owns 32 d)
#define NT 4          // sample-tiles per wave (64 samples)

__device__ __forceinline__ uint bf16h(float x){            // f32 -> bf16 bits, RNE
    uint u = __float_as_uint(x);
    return (u + 0x7fffu + ((u>>16)&1u)) >> 16;
}
__device__ __forceinline__ float bf16f(uint h){ return __uint_as_float(h<<16); }
__device__ __forceinline__ float softplus_f(float x){
    return fmaxf(x,0.f) + log1pf(__expf(-fabsf(x)));
}

// Split W into bf16 hi/lo and pack into MFMA A-fragment order:
// frag (dt,ks): lane l holds W[dt*16 + (l&15)][ks*32 + (l>>4)*8 + i], i=0..7
// => packed[((dt*8+ks)*64 + l)*8 + i]; wave64 load = contiguous 1KB.
__global__ void pack_w_kernel(const float* __restrict__ W1, const float* __restrict__ W2,
                              ushort* __restrict__ ws){
    int idx = blockIdx.x*256 + threadIdx.x;          // 0..65535
    const float* W = blockIdx.y ? W2 : W1;
    ushort* hi = ws + (size_t)blockIdx.y*131072;     // [W1hi|W1lo|W2hi|W2lo], 65536 each
    ushort* lo = hi + 65536;
    float w = W[idx];
    uint h = bf16h(w);
    float l = w - bf16f(h);
    uint l16 = bf16h(l);
    int d = idx >> 8, k = idx & 255;
    int off = ((((d>>4)<<3) + (k>>5))<<9) + (((d&15) | (((k>>3)&3)<<4))<<3) + (k&7);
    hi[off] = (ushort)h;
    lo[off] = (ushort)l16;
}

// NOTE: no min-blocks arg — a (512,2) bound capped VGPRs at 128 and forced
// ~100 regs of scratch spills (FETCH/WRITE showed ~380MB of spill traffic).
// Spill-free needs ~230 VGPRs -> 2 waves/SIMD, 1 block/CU. LDS-BW floor ~92us.
__global__ __launch_bounds__(512)
void ode_mfma_kernel(const float* __restrict__ x, const float* __restrict__ t,
                     const float* __restrict__ b1, const float* __restrict__ u1,
                     const float* __restrict__ b2, const float* __restrict__ u2,
                     const ushort* __restrict__ wpk, float* __restrict__ out)
{
    // Y stage: [row 0..63][hi 256 | lo 256] bf16; 16B granules XOR-swizzled by (row&7)
    // (bank = addr bits 2..6 -> granule bits 0..2; row stride 1024B contributes 0)
    __shared__ __align__(16) ushort ylds[NSAMP*512];

    const int tid  = threadIdx.x;
    const int wv   = tid >> 6;      // wave 0..7 -> d in [32w, 32w+32)
    const int lane = tid & 63;
    const int l15  = lane & 15;
    const int l4   = lane >> 4;
    const int base = blockIdx.x * NSAMP;

    float t0v[NT], rat[NT];
    float y[MT][NT][4], k1[MT][NT][4], k2[MT][NT][4];
    f32x4 acc[MT][NT];

#pragma unroll
    for(int nt=0; nt<NT; nt++){
        int n = base + nt*16 + l15;
        int b = n / (T_LEN*T_LEN);
        int r = n - b*(T_LEN*T_LEN);
        int q = r / T_LEN;
        int j = r - q*T_LEN;
        float ta = t[b*T_LEN + j], tb = t[b*T_LEN + q];
        t0v[nt] = ta; rat[nt] = tb - ta;
        const float* xr = x + (size_t)(b*T_LEN + j)*DM;
#pragma unroll
        for(int mt=0; mt<MT; mt++){
            const int db = 32*wv + mt*16 + l4*4;
            f32x4 v = *(const f32x4*)(xr + db);
#pragma unroll
            for(int r2=0;r2<4;r2++) y[mt][nt][r2] = v[r2];
        }
    }

    // write 4 consecutive-d values (one D-fragment reg group) as hi/lo bf16 into ylds
    auto put = [&](int mt, int nt, float v0, float v1, float v2, float v3){
        uint h0=bf16h(v0), h1=bf16h(v1), h2=bf16h(v2), h3=bf16h(v3);
        uint hp0 = h0 | (h1<<16), hp1 = h2 | (h3<<16);
        uint lp0 = bf16h(v0 - bf16f(h0)) | (bf16h(v1 - bf16f(h1))<<16);
        uint lp1 = bf16h(v2 - bf16f(h2)) | (bf16h(v3 - bf16f(h3))<<16);
        int row = nt*16 + l15;
        int col = 4*wv + 2*mt + (l4>>1);        // logical 16B granule (8 ushort = 8 k)
        int g   = col ^ (row & 7);              // swizzle low 3 granule bits
        int idx = row*512 + g*8 + (l4&1)*4;
        *(uint2*)&ylds[idx]       = make_uint2(hp0, hp1);   // hi half
        *(uint2*)&ylds[idx + 256] = make_uint2(lp0, lp1);   // lo half
    };

    // acc[mt][nt] = (W-slice) x Y^T over K=256, 3-product bf16 split
    auto matmul = [&](const ushort* Whi){
        const ushort* Wlo = Whi + 65536;
#pragma unroll
        for(int mt=0; mt<MT; mt++)
#pragma unroll
            for(int nt=0; nt<NT; nt++)
                acc[mt][nt] = (f32x4){0.f,0.f,0.f,0.f};
#pragma unroll 2
        for(int ks=0; ks<8; ks++){
            bf16x8 ah[MT], al[MT];
#pragma unroll
            for(int mt=0; mt<MT; mt++){
                const int off = ((((2*wv+mt)<<3)+ks)<<9) + (lane<<3);
                ah[mt] = *(const bf16x8*)(Whi + off);
                al[mt] = *(const bf16x8*)(Wlo + off);
            }
            // per-nt B load + its 6 MFMAs: keeps only one (bh,bl) pair live
#pragma unroll
            for(int nt=0; nt<NT; nt++){
                const int row = nt*16 + l15;
                const int gx  = (ks*4 + l4) ^ (row & 7);    // logical granule ks*4+l4
                const ushort* bp = &ylds[row*512 + gx*8];
                bf16x8 bh = *(const bf16x8*)bp;
                bf16x8 bl = *(const bf16x8*)(bp + 256);
#pragma unroll
                for(int mt=0; mt<MT; mt++){
                    acc[mt][nt] = __builtin_amdgcn_mfma_f32_16x16x32_bf16(ah[mt], bh, acc[mt][nt], 0,0,0);
                    acc[mt][nt] = __builtin_amdgcn_mfma_f32_16x16x32_bf16(ah[mt], bl, acc[mt][nt], 0,0,0);
                    acc[mt][nt] = __builtin_amdgcn_mfma_f32_16x16x32_bf16(al[mt], bh, acc[mt][nt], 0,0,0);
                }
            }
        }
    };

    // input already staged by caller; leaves layer-2 raw acc for caller to finish
    auto eval = [&](const float* ttv){
        __syncthreads();                 // stage writes visible
        matmul(wpk);                     // layer 1
        __syncthreads();                 // all reads of input stage done
#pragma unroll
        for(int mt=0; mt<MT; mt++){
            const int db = 32*wv + mt*16 + l4*4;
            f32x4 bv = *(const f32x4*)(b1 + db);
            f32x4 uv = *(const f32x4*)(u1 + db);
#pragma unroll
            for(int nt=0; nt<NT; nt++){
                float v[4];
#pragma unroll
                for(int r2=0;r2<4;r2++)
                    v[r2] = softplus_f(acc[mt][nt][r2] + bv[r2] + ttv[nt]*uv[r2]);
                put(mt, nt, v[0], v[1], v[2], v[3]);
            }
        }
        __syncthreads();
        matmul(wpk + 131072);            // layer 2
    };

    float s0 = 0.f;
#pragma unroll 1
    for(int step=0; step<3; step++){
        const float s1 = (step==0) ? 0.1127016653792583f : ((step==1) ? 0.5f : 0.8872983346207417f);
        const float gw = ((step==1) ? 0.88888f : 0.55555f) * 0.5f;
        const float dt = s1 - s0;
        const float c3 = dt * (1.f/3.f);
        const float dt8 = dt * 0.125f;
        float tt[NT];

        // ---- eval 1: f(s0, y) -> k1
        __syncthreads();                 // prior step's transpose reads done
#pragma unroll
        for(int mt=0; mt<MT; mt++)
#pragma unroll
            for(int nt=0; nt<NT; nt++)
                put(mt, nt, y[mt][nt][0], y[mt][nt][1], y[mt][nt][2], y[mt][nt][3]);
#pragma unroll
        for(int nt=0; nt<NT; nt++) tt[nt] = t0v[nt] + s0*rat[nt];
        eval(tt);

        // ---- k1 extract; stage y + (dt/3)k1
        __syncthreads();
#pragma unroll
        for(int mt=0; mt<MT; mt++){
            const int db = 32*wv + mt*16 + l4*4;
            f32x4 bv = *(const f32x4*)(b2 + db);
            f32x4 uv = *(const f32x4*)(u2 + db);
#pragma unroll
            for(int nt=0; nt<NT; nt++){
                float v[4];
#pragma unroll
                for(int r2=0;r2<4;r2++){
                    float kk = (acc[mt][nt][r2] + bv[r2] + tt[nt]*uv[r2]) * rat[nt];
                    k1[mt][nt][r2] = kk;
                    v[r2] = fmaf(c3, kk, y[mt][nt][r2]);
                }
                put(mt, nt, v[0], v[1], v[2], v[3]);
            }
        }
#pragma unroll
        for(int nt=0; nt<NT; nt++) tt[nt] = t0v[nt] + (s0+c3)*rat[nt];
        eval(tt);

        // ---- k2 extract; stage y + dt*k2 - (dt/3)k1
        __syncthreads();
#pragma unroll
        for(int mt=0; mt<MT; mt++){
            const int db = 32*wv + mt*16 + l4*4;
            f32x4 bv = *(const f32x4*)(b2 + db);
            f32x4 uv = *(const f32x4*)(u2 + db);
#pragma unroll
            for(int nt=0; nt<NT; nt++){
                float v[4];
#pragma unroll
                for(int r2=0;r2<4;r2++){
                    float kk = (acc[mt][nt][r2] + bv[r2] + tt[nt]*uv[r2]) * rat[nt];
                    k2[mt][nt][r2] = kk;
                    v[r2] = y[mt][nt][r2] + dt*kk - c3*k1[mt][nt][r2];
                }
                put(mt, nt, v[0], v[1], v[2], v[3]);
            }
        }
#pragma unroll
        for(int nt=0; nt<NT; nt++) tt[nt] = t0v[nt] + (s0+2.f*c3)*rat[nt];
        eval(tt);

        // ---- k3 extract (folded): stage y + dt*(k1-k2+k3); y += dt8*(k1+3(k2+k3))
        __syncthreads();
#pragma unroll
        for(int mt=0; mt<MT; mt++){
            const int db = 32*wv + mt*16 + l4*4;
            f32x4 bv = *(const f32x4*)(b2 + db);
            f32x4 uv = *(const f32x4*)(u2 + db);
#pragma unroll
            for(int nt=0; nt<NT; nt++){
                float v[4];
#pragma unroll
                for(int r2=0;r2<4;r2++){
                    float k3v = (acc[mt][nt][r2] + bv[r2] + tt[nt]*uv[r2]) * rat[nt];
                    float yo = y[mt][nt][r2];
                    v[r2] = yo + dt*(k1[mt][nt][r2] - k2[mt][nt][r2] + k3v);
                    y[mt][nt][r2] = yo + dt8*(k1[mt][nt][r2] + 3.f*(k2[mt][nt][r2] + k3v));
                }
                put(mt, nt, v[0], v[1], v[2], v[3]);
            }
        }
#pragma unroll
        for(int nt=0; nt<NT; nt++) tt[nt] = t0v[nt] + s1*rat[nt];
        eval(tt);

        // ---- k4 fold, then transpose through LDS for coalesced output
        __syncthreads();                 // matmul2 reads of ylds done; safe to overwrite
        {
            float* yf = (float*)ylds;    // view: [64 rows][256 f32], 16B-granule swizzled
#pragma unroll
            for(int mt=0; mt<MT; mt++){
                const int db = 32*wv + mt*16 + l4*4;
                f32x4 bv = *(const f32x4*)(b2 + db);
                f32x4 uv = *(const f32x4*)(u2 + db);
#pragma unroll
                for(int nt=0; nt<NT; nt++){
                    const int row = nt*16 + l15;
                    f32x4 ov;
#pragma unroll
                    for(int r2=0;r2<4;r2++){
                        float k4v = (acc[mt][nt][r2] + bv[r2] + tt[nt]*uv[r2]) * rat[nt];
                        float yn = fmaf(dt8, k4v, y[mt][nt][r2]);
                        y[mt][nt][r2] = yn;
                        ov[r2] = yn * gw;
                    }
                    const int c = 8*wv + 4*mt + l4;          // logical 16B granule = d>>2
                    const int p = c ^ (row & 7);
                    *(f32x4*)&yf[row*256 + p*4] = ov;
                }
            }
            __syncthreads();
            // each wave stores 8 rows, 1KB contiguous per row — non-temporal
#pragma unroll
            for(int i=0;i<8;i++){
                const int r = 8*wv + i;
                f32x4 v = *(const f32x4*)&yf[r*256 + (lane ^ i)*4];
                __builtin_nontemporal_store(v,
                    (f32x4*)(out + ((size_t)(base + r)*3 + step)*DM + lane*4));
            }
        }
        s0 = s1;
    }
}

extern "C" void kernel_launch(void* const* d_in, const int* in_sizes, int n_in,
                              void* d_out, int out_size, void* d_ws, size_t ws_size,
                              hipStream_t stream)
{
    const float* x  = (const float*)d_in[0];
    const float* t  = (const float*)d_in[1];
    const float* W1 = (const float*)d_in[2];
    const float* b1 = (const float*)d_in[3];
    const float* u1 = (const float*)d_in[4];
    const float* W2 = (const float*)d_in[5];
    const float* b2 = (const float*)d_in[6];
    const float* u2 = (const float*)d_in[7];
    ushort* wpk = (ushort*)d_ws;     // 512 KB: W1hi|W1lo|W2hi|W2lo packed fragments

    pack_w_kernel<<<dim3(256,2), 256, 0, stream>>>(W1, W2, wpk);
    ode_mfma_kernel<<<dim3((4*T_LEN*T_LEN)/NSAMP), 512, 0, stream>>>(
        x, t, b1, u1, b2, u2, wpk, (float*)d_out);
}

// Round 6
// 1025.443 us; speedup vs baseline: 1.4817x; 1.4327x over previous
//
#include <hip/hip_runtime.h>

typedef float f32x4 __attribute__((ext_vector_type(4)));
typedef short bf16x8 __attribute__((ext_vector_type(8)));

#define T_LEN 96
#define DM    256
#define NSAMP 64      // ODE rows per block
#define MT 2          // d-tiles per wave (wave owns 32 d)
#define NT 2          // sample-tiles per wave (wave group owns 32 samples)

__device__ __forceinline__ uint bf16h(float x){            // f32 -> bf16 bits, RNE
    uint u = __float_as_uint(x);
    return (u + 0x7fffu + ((u>>16)&1u)) >> 16;
}
__device__ __forceinline__ float bf16f(uint h){ return __uint_as_float(h<<16); }
__device__ __forceinline__ float softplus_f(float x){
    return fmaxf(x,0.f) + log1pf(__expf(-fabsf(x)));
}

// Split W into bf16 hi/lo and pack into MFMA A-fragment order:
// frag (dt,ks): lane l holds W[dt*16 + (l&15)][ks*32 + (l>>4)*8 + i], i=0..7
// => packed[((dt*8+ks)*64 + l)*8 + i]; wave64 load = contiguous 1KB.
__global__ void pack_w_kernel(const float* __restrict__ W1, const float* __restrict__ W2,
                              ushort* __restrict__ ws){
    int idx = blockIdx.x*256 + threadIdx.x;          // 0..65535
    const float* W = blockIdx.y ? W2 : W1;
    ushort* hi = ws + (size_t)blockIdx.y*131072;     // [W1hi|W1lo|W2hi|W2lo], 65536 each
    ushort* lo = hi + 65536;
    float w = W[idx];
    uint h = bf16h(w);
    float l = w - bf16f(h);
    uint l16 = bf16h(l);
    int d = idx >> 8, k = idx & 255;
    int off = ((((d>>4)<<3) + (k>>5))<<9) + (((d&15) | (((k>>3)&3)<<4))<<3) + (k&7);
    hi[off] = (ushort)h;
    lo[off] = (ushort)l16;
}

// 16 waves: group g=wv>>3 owns samples [32g,32g+32); wave d-slice wvd=wv&7 owns
// d in [32*wvd, 32*wvd+32). Per-thread ODE state = 48 f32 (was 96 -> spilled:
// block state 192KB is structural, so spread it over 2x threads).
__global__ __launch_bounds__(1024)
void ode_mfma_kernel(const float* __restrict__ x, const float* __restrict__ t,
                     const float* __restrict__ b1, const float* __restrict__ u1,
                     const float* __restrict__ b2, const float* __restrict__ u2,
                     const ushort* __restrict__ wpk, float* __restrict__ out)
{
    // Y stage: [row 0..63][hi 256 | lo 256] bf16; 16B granules XOR-swizzled by (row&7)
    __shared__ __align__(16) ushort ylds[NSAMP*512];

    const int tid  = threadIdx.x;
    const int wv   = tid >> 6;       // 0..15
    const int wvd  = wv & 7;         // d-slice owner
    const int grp  = wv >> 3;        // sample group
    const int lane = tid & 63;
    const int l15  = lane & 15;
    const int l4   = lane >> 4;
    const int base = blockIdx.x * NSAMP;

    float t0v[NT], rat[NT];
    float y[MT][NT][4], k1[MT][NT][4], k2[MT][NT][4];
    f32x4 acc[MT][NT];

#pragma unroll
    for(int nt=0; nt<NT; nt++){
        int n = base + grp*32 + nt*16 + l15;
        int b = n / (T_LEN*T_LEN);
        int r = n - b*(T_LEN*T_LEN);
        int q = r / T_LEN;
        int j = r - q*T_LEN;
        float ta = t[b*T_LEN + j], tb = t[b*T_LEN + q];
        t0v[nt] = ta; rat[nt] = tb - ta;
        const float* xr = x + (size_t)(b*T_LEN + j)*DM;
#pragma unroll
        for(int mt=0; mt<MT; mt++){
            const int db = 32*wvd + mt*16 + l4*4;
            f32x4 v = *(const f32x4*)(xr + db);
#pragma unroll
            for(int r2=0;r2<4;r2++) y[mt][nt][r2] = v[r2];
        }
    }

    // write 4 consecutive-d values (one D-fragment reg group) as hi/lo bf16 into ylds
    auto put = [&](int mt, int nt, float v0, float v1, float v2, float v3){
        uint h0=bf16h(v0), h1=bf16h(v1), h2=bf16h(v2), h3=bf16h(v3);
        uint hp0 = h0 | (h1<<16), hp1 = h2 | (h3<<16);
        uint lp0 = bf16h(v0 - bf16f(h0)) | (bf16h(v1 - bf16f(h1))<<16);
        uint lp1 = bf16h(v2 - bf16f(h2)) | (bf16h(v3 - bf16f(h3))<<16);
        int row = grp*32 + nt*16 + l15;
        int col = 4*wvd + 2*mt + (l4>>1);       // logical 16B granule (8 k)
        int g   = col ^ (row & 7);              // swizzle low 3 granule bits
        int idx = row*512 + g*8 + (l4&1)*4;
        *(uint2*)&ylds[idx]       = make_uint2(hp0, hp1);   // hi half
        *(uint2*)&ylds[idx + 256] = make_uint2(lp0, lp1);   // lo half
    };

    // acc[mt][nt] = (W-slice) x Y^T over K=256, 3-product bf16 split
    auto matmul = [&](const ushort* Whi){
        const ushort* Wlo = Whi + 65536;
#pragma unroll
        for(int mt=0; mt<MT; mt++)
#pragma unroll
            for(int nt=0; nt<NT; nt++)
                acc[mt][nt] = (f32x4){0.f,0.f,0.f,0.f};
#pragma unroll 2
        for(int ks=0; ks<8; ks++){
            bf16x8 ah[MT], al[MT];
#pragma unroll
            for(int mt=0; mt<MT; mt++){
                const int off = ((((2*wvd+mt)<<3)+ks)<<9) + (lane<<3);
                ah[mt] = *(const bf16x8*)(Whi + off);
                al[mt] = *(const bf16x8*)(Wlo + off);
            }
#pragma unroll
            for(int nt=0; nt<NT; nt++){
                const int row = grp*32 + nt*16 + l15;
                const int gx  = (ks*4 + l4) ^ (row & 7);
                const ushort* bp = &ylds[row*512 + gx*8];
                bf16x8 bh = *(const bf16x8*)bp;
                bf16x8 bl = *(const bf16x8*)(bp + 256);
#pragma unroll
                for(int mt=0; mt<MT; mt++){
                    acc[mt][nt] = __builtin_amdgcn_mfma_f32_16x16x32_bf16(ah[mt], bh, acc[mt][nt], 0,0,0);
                    acc[mt][nt] = __builtin_amdgcn_mfma_f32_16x16x32_bf16(ah[mt], bl, acc[mt][nt], 0,0,0);
                    acc[mt][nt] = __builtin_amdgcn_mfma_f32_16x16x32_bf16(al[mt], bh, acc[mt][nt], 0,0,0);
                }
            }
        }
    };

    // input already staged by caller; leaves layer-2 raw acc for caller to finish
    auto eval = [&](const float* ttv){
        __syncthreads();                 // stage writes visible
        matmul(wpk);                     // layer 1
        __syncthreads();                 // all reads of input stage done
#pragma unroll
        for(int mt=0; mt<MT; mt++){
            const int db = 32*wvd + mt*16 + l4*4;
            f32x4 bv = *(const f32x4*)(b1 + db);
            f32x4 uv = *(const f32x4*)(u1 + db);
#pragma unroll
            for(int nt=0; nt<NT; nt++){
                float v[4];
#pragma unroll
                for(int r2=0;r2<4;r2++)
                    v[r2] = softplus_f(acc[mt][nt][r2] + bv[r2] + ttv[nt]*uv[r2]);
                put(mt, nt, v[0], v[1], v[2], v[3]);
            }
        }
        __syncthreads();
        matmul(wpk + 131072);            // layer 2
    };

    float s0 = 0.f;
#pragma unroll 1
    for(int step=0; step<3; step++){
        const float s1 = (step==0) ? 0.1127016653792583f : ((step==1) ? 0.5f : 0.8872983346207417f);
        const float gw = ((step==1) ? 0.88888f : 0.55555f) * 0.5f;
        const float dt = s1 - s0;
        const float c3 = dt * (1.f/3.f);
        const float dt8 = dt * 0.125f;
        float tt[NT];

        // ---- eval 1: f(s0, y) -> k1
        __syncthreads();                 // prior step's transpose reads done
#pragma unroll
        for(int mt=0; mt<MT; mt++)
#pragma unroll
            for(int nt=0; nt<NT; nt++)
                put(mt, nt, y[mt][nt][0], y[mt][nt][1], y[mt][nt][2], y[mt][nt][3]);
#pragma unroll
        for(int nt=0; nt<NT; nt++) tt[nt] = t0v[nt] + s0*rat[nt];
        eval(tt);

        // ---- k1 extract; stage y + (dt/3)k1
        __syncthreads();
#pragma unroll
        for(int mt=0; mt<MT; mt++){
            const int db = 32*wvd + mt*16 + l4*4;
            f32x4 bv = *(const f32x4*)(b2 + db);
            f32x4 uv = *(const f32x4*)(u2 + db);
#pragma unroll
            for(int nt=0; nt<NT; nt++){
                float v[4];
#pragma unroll
                for(int r2=0;r2<4;r2++){
                    float kk = (acc[mt][nt][r2] + bv[r2] + tt[nt]*uv[r2]) * rat[nt];
                    k1[mt][nt][r2] = kk;
                    v[r2] = fmaf(c3, kk, y[mt][nt][r2]);
                }
                put(mt, nt, v[0], v[1], v[2], v[3]);
            }
        }
#pragma unroll
        for(int nt=0; nt<NT; nt++) tt[nt] = t0v[nt] + (s0+c3)*rat[nt];
        eval(tt);

        // ---- k2 extract; stage y + dt*k2 - (dt/3)k1
        __syncthreads();
#pragma unroll
        for(int mt=0; mt<MT; mt++){
            const int db = 32*wvd + mt*16 + l4*4;
            f32x4 bv = *(const f32x4*)(b2 + db);
            f32x4 uv = *(const f32x4*)(u2 + db);
#pragma unroll
            for(int nt=0; nt<NT; nt++){
                float v[4];
#pragma unroll
                for(int r2=0;r2<4;r2++){
                    float kk = (acc[mt][nt][r2] + bv[r2] + tt[nt]*uv[r2]) * rat[nt];
                    k2[mt][nt][r2] = kk;
                    v[r2] = y[mt][nt][r2] + dt*kk - c3*k1[mt][nt][r2];
                }
                put(mt, nt, v[0], v[1], v[2], v[3]);
            }
        }
#pragma unroll
        for(int nt=0; nt<NT; nt++) tt[nt] = t0v[nt] + (s0+2.f*c3)*rat[nt];
        eval(tt);

        // ---- k3 extract (folded): stage y + dt*(k1-k2+k3); y += dt8*(k1+3(k2+k3))
        __syncthreads();
#pragma unroll
        for(int mt=0; mt<MT; mt++){
            const int db = 32*wvd + mt*16 + l4*4;
            f32x4 bv = *(const f32x4*)(b2 + db);
            f32x4 uv = *(const f32x4*)(u2 + db);
#pragma unroll
            for(int nt=0; nt<NT; nt++){
                float v[4];
#pragma unroll
                for(int r2=0;r2<4;r2++){
                    float k3v = (acc[mt][nt][r2] + bv[r2] + tt[nt]*uv[r2]) * rat[nt];
                    float yo = y[mt][nt][r2];
                    v[r2] = yo + dt*(k1[mt][nt][r2] - k2[mt][nt][r2] + k3v);
                    y[mt][nt][r2] = yo + dt8*(k1[mt][nt][r2] + 3.f*(k2[mt][nt][r2] + k3v));
                }
                put(mt, nt, v[0], v[1], v[2], v[3]);
            }
        }
#pragma unroll
        for(int nt=0; nt<NT; nt++) tt[nt] = t0v[nt] + s1*rat[nt];
        eval(tt);

        // ---- k4 fold, then transpose through LDS for coalesced output
        __syncthreads();                 // matmul2 reads of ylds done; safe to overwrite
        {
            float* yf = (float*)ylds;    // view: [64 rows][256 f32], 16B-granule swizzled
#pragma unroll
            for(int mt=0; mt<MT; mt++){
                const int db = 32*wvd + mt*16 + l4*4;
                f32x4 bv = *(const f32x4*)(b2 + db);
                f32x4 uv = *(const f32x4*)(u2 + db);
#pragma unroll
                for(int nt=0; nt<NT; nt++){
                    const int row = grp*32 + nt*16 + l15;
                    f32x4 ov;
#pragma unroll
                    for(int r2=0;r2<4;r2++){
                        float k4v = (acc[mt][nt][r2] + bv[r2] + tt[nt]*uv[r2]) * rat[nt];
                        float yn = fmaf(dt8, k4v, y[mt][nt][r2]);
                        y[mt][nt][r2] = yn;
                        ov[r2] = yn * gw;
                    }
                    const int c = 8*wvd + 4*mt + l4;         // logical 16B granule = d>>2
                    const int p = c ^ (row & 7);
                    *(f32x4*)&yf[row*256 + p*4] = ov;
                }
            }
            __syncthreads();
            // each wave stores 4 rows, 1KB contiguous per row — non-temporal
#pragma unroll
            for(int i=0;i<4;i++){
                const int r = 4*wv + i;
                f32x4 v = *(const f32x4*)&yf[r*256 + ((lane ^ (r&7))&63)*4];
                __builtin_nontemporal_store(v,
                    (f32x4*)(out + ((size_t)(base + r)*3 + step)*DM + lane*4));
            }
        }
        s0 = s1;
    }
}

extern "C" void kernel_launch(void* const* d_in, const int* in_sizes, int n_in,
                              void* d_out, int out_size, void* d_ws, size_t ws_size,
                              hipStream_t stream)
{
    const float* x  = (const float*)d_in[0];
    const float* t  = (const float*)d_in[1];
    const float* W1 = (const float*)d_in[2];
    const float* b1 = (const float*)d_in[3];
    const float* u1 = (const float*)d_in[4];
    const float* W2 = (const float*)d_in[5];
    const float* b2 = (const float*)d_in[6];
    const float* u2 = (const float*)d_in[7];
    ushort* wpk = (ushort*)d_ws;     // 512 KB: W1hi|W1lo|W2hi|W2lo packed fragments

    pack_w_kernel<<<dim3(256,2), 256, 0, stream>>>(W1, W2, wpk);
    ode_mfma_kernel<<<dim3((4*T_LEN*T_LEN)/NSAMP), 1024, 0, stream>>>(
        x, t, b1, u1, b2, u2, wpk, (float*)d_out);
}